// Round 13
// baseline (3659.558 us; speedup 1.0000x reference)
//
#include <hip/hip_runtime.h>

// ============================================================================
// GRU_29300266893722  (B=64, T=512, IN=256, H=1024, OUT=256)  -- MI355X gfx950
//
// R14 = R13 (k_scan 2990us) + residual-latency micro-reorders on the same
// overlap axis that produced R11 (-11%) and R13 (-5%):
//  (1) phase B issues its 16 exchange loads FIRST (before xz/xr loads and
//      vr0 prefetch) -- detection flight starts earlier, vm8-tie not queued
//      behind prefetch retires;
//  (2) phase A issues exchange loads before the xh loads (same reasoning);
//  (3) poll backoff sleep deferred to round >=4: polls now succeed in ~1-2
//      rounds (FETCH 1.15GB ~ 12% over floor), so the round-2 sleep DELAYS
//      detection on the common retry path.
// Structural options examined and rejected: full-K-per-wave (VGPR budget:
// Vz+Wh resident + 4x staging > 256, or re-exposes weight stream in tail =
// 1:1 cost per R12); 8x128-col chains (half-empty MFMA tiles).
// History: R8 z-deferral -5.5%; R9.1 backoff null (at ~7 rounds); R10
// atomic publish null; R11 split-poll -11%; R12 residency swap +5.6%
// (reverted); R13 loads-before-z-finish -5%.
// ============================================================================

#define BB 64
#define TT 512
#define KIN 256
#define HH 1024
#define NOUT 256

typedef float  f32x4 __attribute__((ext_vector_type(4)));
typedef short  s16x8 __attribute__((ext_vector_type(8)));
typedef unsigned int u32x4 __attribute__((ext_vector_type(4)));
typedef unsigned short u16x4 __attribute__((ext_vector_type(4)));

#define MFMA16(a, b, c) __builtin_amdgcn_mfma_f32_16x16x32_bf16((a), (b), (c), 0, 0, 0)

static __device__ __forceinline__ s16x8 as16(u32x4 v) { return __builtin_bit_cast(s16x8, v); }

static __device__ __forceinline__ unsigned short f2bf(float f) {
  unsigned u = __float_as_uint(f);
  u += 0x7FFFu + ((u >> 16) & 1u);   // round-to-nearest-even
  return (unsigned short)(u >> 16);
}
static __device__ __forceinline__ float bf2f(unsigned short h) {
  return __uint_as_float(((unsigned)h) << 16);
}

static __device__ __forceinline__ float tanh_fast(float x) {
  float xc = fminf(fmaxf(x, -15.f), 15.f);
  float e = __expf(2.f * xc);
  return (e - 1.f) / (e + 1.f);
}
static __device__ __forceinline__ float sigmoid_fast(float x) {
  float xc = fminf(fmaxf(x, -30.f), 30.f);
  return 1.f / (1.f + __expf(-xc));
}

// ---- device-scope (IF-coherent) access helpers -----------------------------
static __device__ __forceinline__ void st_dw(unsigned* p, unsigned v) {
  asm volatile("global_store_dword %0, %1, off sc0 sc1" :: "v"(p), "v"(v) : "memory");
}
template <int OFF>
static __device__ __forceinline__ void ld128o(u32x4& d, const unsigned* p) {
  asm volatile("global_load_dwordx4 %0, %1, off offset:%2 sc0 sc1"
               : "=v"(d) : "v"(p), "i"(OFF));
}
// tie 8 regs behind "first 8 of the outstanding queue retired" (in-order vmcnt)
static __device__ __forceinline__ void tie8_vm8(u32x4& a0, u32x4& a1, u32x4& a2, u32x4& a3,
                                                u32x4& a4, u32x4& a5, u32x4& a6, u32x4& a7) {
  asm volatile("s_waitcnt vmcnt(8)"
               : "+v"(a0), "+v"(a1), "+v"(a2), "+v"(a3),
                 "+v"(a4), "+v"(a5), "+v"(a6), "+v"(a7) :: "memory");
}
static __device__ __forceinline__ void tie8_vm0(u32x4& a0, u32x4& a1, u32x4& a2, u32x4& a3,
                                                u32x4& a4, u32x4& a5, u32x4& a6, u32x4& a7) {
  asm volatile("s_waitcnt vmcnt(0)"
               : "+v"(a0), "+v"(a1), "+v"(a2), "+v"(a3),
                 "+v"(a4), "+v"(a5), "+v"(a6), "+v"(a7) :: "memory");
}

#define CHK4(R) (((R).x ^ tag) | ((R).y ^ tag) | ((R).z ^ tag) | ((R).w ^ tag))

// pack two tagged-dword quads (cols j0..3, j4..7) into one bf16x8 frag quad
static __device__ __forceinline__ unsigned pk(unsigned hi, unsigned lo) {
  return __builtin_amdgcn_perm(hi, lo, 0x07060302u);
}
static __device__ __forceinline__ u32x4 pack_frag(u32x4 a, u32x4 b) {
  u32x4 r;
  r.x = pk(a.y, a.x); r.y = pk(a.w, a.z);
  r.z = pk(b.y, b.x); r.w = pk(b.w, b.z);
  return r;
}

// slow path: poll one half (2 base pointers, 8 regs) to completion.
// R14: sleep only after round 4 (common retry is 1-2 rounds; early sleep
// delays detection).
static __device__ __forceinline__ void poll8(
    const unsigned* pa, const unsigned* pb, unsigned tag, bool& dead,
    u32x4& r0, u32x4& r1, u32x4& r2, u32x4& r3,
    u32x4& r4, u32x4& r5, u32x4& r6, u32x4& r7) {
  int guard = 0;
  while (true) {
    ld128o<0>(r0, pa); ld128o<1024>(r1, pa); ld128o<2048>(r2, pa); ld128o<3072>(r3, pa);
    ld128o<0>(r4, pb); ld128o<1024>(r5, pb); ld128o<2048>(r6, pb); ld128o<3072>(r7, pb);
    tie8_vm0(r0, r1, r2, r3, r4, r5, r6, r7);
    unsigned bad = (CHK4(r0) | CHK4(r1) | CHK4(r2) | CHK4(r3) |
                    CHK4(r4) | CHK4(r5) | CHK4(r6) | CHK4(r7)) & 0xFFFFu;
    if (__all(bad == 0)) break;
    if (dead || ++guard > 4096) { dead = true; break; }
    if (guard > 4) __builtin_amdgcn_s_sleep(4);
  }
}

// ---- workspace layout ------------------------------------------------------
static constexpr size_t SZ_XP   = (size_t)TT * BB * HH * 2;       // 64 MB
static constexpr size_t OFF_XH  = 0;
static constexpr size_t OFF_XZ  = OFF_XH + SZ_XP;
static constexpr size_t OFF_XR  = OFF_XZ + SZ_XP;
static constexpr size_t OFF_XB  = OFF_XR + SZ_XP;                 // X bf16
static constexpr size_t OFF_WHP = OFF_XB + (size_t)BB * TT * KIN * 2;
static constexpr size_t OFF_VZP = OFF_WHP + (size_t)HH * HH * 2;
static constexpr size_t OFF_VRP = OFF_VZP + (size_t)HH * HH * 2;
static constexpr size_t OFF_WXP = OFF_VRP + (size_t)HH * HH * 2;
static constexpr size_t OFF_UZP = OFF_WXP + (size_t)HH * KIN * 2;
static constexpr size_t OFF_URP = OFF_UZP + (size_t)HH * KIN * 2;
static constexpr size_t OFF_HB  = OFF_URP + (size_t)HH * KIN * 2; // 4*16*1024 tagged dwords
static constexpr size_t OFF_HRB = OFF_HB + (size_t)4 * 16 * HH * 4;
static constexpr size_t OFF_HF  = OFF_HRB + (size_t)4 * 16 * HH * 4;  // final h fp32

// ============================================================================
// K1: X fp32 -> bf16
// ============================================================================
__global__ void __launch_bounds__(256) k_convert_x(const float* __restrict__ X,
                                                   unsigned short* __restrict__ Xb) {
  size_t i = ((size_t)blockIdx.x * 256 + threadIdx.x) * 4;
  f32x4 v = *(const f32x4*)(X + i);
  u16x4 o = { f2bf(v[0]), f2bf(v[1]), f2bf(v[2]), f2bf(v[3]) };
  *(u16x4*)(Xb + i) = o;
}

// ============================================================================
// K2: pack weights W[1024][K] fp32 -> bf16 MFMA B-fragment layout
// ============================================================================
__global__ void __launch_bounds__(256) k_pack_w(
    const float* __restrict__ Wh, const float* __restrict__ Vz, const float* __restrict__ Vr,
    const float* __restrict__ Wx, const float* __restrict__ Uz, const float* __restrict__ Ur,
    unsigned short* __restrict__ Whp, unsigned short* __restrict__ Vzp, unsigned short* __restrict__ Vrp,
    unsigned short* __restrict__ Wxp, unsigned short* __restrict__ Uzp, unsigned short* __restrict__ Urp) {
  int z = blockIdx.y;
  const float* src; unsigned short* dst; int K;
  switch (z) {
    case 0: src = Wh; dst = Whp; K = 1024; break;
    case 1: src = Vz; dst = Vzp; K = 1024; break;
    case 2: src = Vr; dst = Vrp; K = 1024; break;
    case 3: src = Wx; dst = Wxp; K = 256;  break;
    case 4: src = Uz; dst = Uzp; K = 256;  break;
    default: src = Ur; dst = Urp; K = 256; break;
  }
  int KK = K >> 5;
  int total = 64 * KK * 64;
  int tau = blockIdx.x * 256 + threadIdx.x;
  if (tau >= total) return;
  int lane = tau & 63;
  int kk = (tau >> 6) % KK;
  int ct = tau / (KK * 64);
  int q = lane >> 4, cl = lane & 15;
  const float* s = src + (size_t)(ct * 16 + cl) * K + kk * 32 + q * 8;
  f32x4 v0 = *(const f32x4*)s;
  f32x4 v1 = *(const f32x4*)(s + 4);
  u32x4 o;
  o.x = (unsigned)f2bf(v0[0]) | ((unsigned)f2bf(v0[1]) << 16);
  o.y = (unsigned)f2bf(v0[2]) | ((unsigned)f2bf(v0[3]) << 16);
  o.z = (unsigned)f2bf(v1[0]) | ((unsigned)f2bf(v1[1]) << 16);
  o.w = (unsigned)f2bf(v1[2]) | ((unsigned)f2bf(v1[3]) << 16);
  *(u32x4*)(dst + (size_t)tau * 8) = o;
}

// ============================================================================
// K3: XH/XZ/XR[t][b][h] (bf16) = X @ {Wx,Uz,Ur}^T + bias.  grid (512,16,3).
// ============================================================================
__global__ void __launch_bounds__(256) k_proj(
    const unsigned short* __restrict__ Xb,
    const unsigned short* __restrict__ Wxp, const unsigned short* __restrict__ Uzp,
    const unsigned short* __restrict__ Urp,
    const float* __restrict__ bx, const float* __restrict__ bz, const float* __restrict__ br,
    unsigned short* __restrict__ XH, unsigned short* __restrict__ XZ, unsigned short* __restrict__ XR) {
  __shared__ u32x4 As[4 * 8 * 64];  // 32 KB
  const int tid = threadIdx.x;
  const int mb = blockIdx.x, cb = blockIdx.y, mu = blockIdx.z;

#pragma unroll
  for (int i = 0; i < 8; ++i) {
    int fid = i * 256 + tid;
    int lane = fid & 63, kk = (fid >> 6) & 7, rt = fid >> 9;
    int q = lane >> 4, cl = lane & 15;
    int mrow = mb * 64 + rt * 16 + cl;
    As[fid] = *(const u32x4*)(Xb + (size_t)mrow * KIN + kk * 32 + q * 8);
  }
  __syncthreads();

  const int lane = tid & 63, w = tid >> 6;
  const int q = lane >> 4, cl = lane & 15;
  const unsigned short* Bp = (mu == 0) ? Wxp : (mu == 1) ? Uzp : Urp;
  const float* bias        = (mu == 0) ? bx  : (mu == 1) ? bz  : br;
  unsigned short* Dst      = (mu == 0) ? XH  : (mu == 1) ? XZ  : XR;

  f32x4 z4 = {0.f, 0.f, 0.f, 0.f};
  f32x4 acc[4] = {z4, z4, z4, z4};
  const int ctg = cb * 4 + w;
#pragma unroll
  for (int kk = 0; kk < 8; ++kk) {
    u32x4 b = *(const u32x4*)(Bp + ((size_t)(ctg * 8 + kk) * 64 + lane) * 8);
#pragma unroll
    for (int rt = 0; rt < 4; ++rt)
      acc[rt] = MFMA16(as16(As[(rt * 8 + kk) * 64 + lane]), as16(b), acc[rt]);
  }
  const int col = cb * 64 + w * 16 + cl;
  const float bv = bias[col];
#pragma unroll
  for (int rt = 0; rt < 4; ++rt) {
#pragma unroll
    for (int j = 0; j < 4; ++j) {
      int m = mb * 64 + rt * 16 + q * 4 + j;   // m = b*512 + t
      int t = m & (TT - 1), b = m >> 9;
      Dst[((size_t)t * BB + b) * HH + col] = f2bf(acc[rt][j] + bv);
    }
  }
}

// ============================================================================
// K4: persistent scan, tag-in-data, fragment-major exchange buffers.
//   64 blocks x 256 threads. chain g = blk>>4, col-block c = blk&15.
//   wave w: K-slice [256w,256w+256), owns cols c*64+w*16+cl, rows q*4+j.
//   R11: split-poll + early MFMA; R13: loads before z-finish;
//   R14: exchange loads absolutely first in both phases; late-only backoff.
// ============================================================================
__global__ void __launch_bounds__(256, 1) k_scan(
    const unsigned short* __restrict__ XH, const unsigned short* __restrict__ XZ,
    const unsigned short* __restrict__ XR,
    const unsigned short* __restrict__ Whp, const unsigned short* __restrict__ Vzp,
    const unsigned short* __restrict__ Vrp,
    unsigned* __restrict__ hb32all, unsigned* __restrict__ hrb32all,
    float* __restrict__ hfinal) {
  __shared__ f32x4 redA[16 * 64];  // 16 KB
  __shared__ f32x4 redB[16 * 64];  // 16 KB  (z-partials; reduced next step)
  __shared__ f32x4 redC[16 * 64];  // 16 KB

  const int tid = threadIdx.x;
  const int lane = tid & 63, w = tid >> 6;
  const int q = lane >> 4, cl = lane & 15;
  const int blk = blockIdx.x;
  const int g = blk >> 4, c = blk & 15;   // chain, col-block
  const int c4 = c * 4, kw = w * 8;

  unsigned* hb  = hb32all  + (size_t)g * 16 * HH;
  unsigned* hrb = hrb32all + (size_t)g * 16 * HH;

  // resident weight fragments: Wh + Vz (256 VGPRs); Vr streamed per step
  u32x4 wh[4][8], vz[4][8];
#pragma unroll
  for (int ct = 0; ct < 4; ++ct)
#pragma unroll
    for (int k = 0; k < 8; ++k) {
      size_t fi = (((size_t)(c4 + ct) * 32 + kw + k) * 64 + lane) * 8;
      wh[ct][k] = *(const u32x4*)(Whp + fi);
      vz[ct][k] = *(const u32x4*)(Vzp + fi);
    }

  const int hcol = c * 64 + w * 16 + cl;         // owned output column
  const int brow0 = g * 16 + q * 4;              // owned batch rows (+j)

  // consumer read bases (fragment-major): buf + w*4096 + lane*4 dwords
  const unsigned* rpA = hrb + w * 4096 + lane * 4;
  const unsigned* rpB = hb  + w * 4096 + lane * 4;
  // producer store bases
  const unsigned C = (unsigned)hcol;
  const unsigned sbase = ((C >> 8) * 8 + ((C >> 5) & 7)) * 512 + ((C >> 2) & 1) * 256 +
                         (((C >> 3) & 3) * 16 + q * 4) * 4 + (C & 3);
  unsigned* spA = hb  + sbase;    // row j store at + j*4
  unsigned* spB = hrb + sbase;

  const f32x4 z4 = {0.f, 0.f, 0.f, 0.f};
  f32x4 hreg = z4, zreg = z4;
  unsigned short xz_u[4] = {0, 0, 0, 0};  // carried across steps (deferred z)
  bool dead = false;

  for (int t = 0; t < TT; ++t) {
    // ---------------- phase A: h update ----------------
    unsigned short xh_u[4];
    f32x4 acc[4] = {z4, z4, z4, z4};
    if (t > 0) {
      const unsigned tag = (unsigned)t;
      const unsigned* p1 = rpA + 1024;
      const unsigned* p2 = rpA + 2048;
      const unsigned* p3 = rpA + 3072;
      u32x4 r0, r1, r2, r3, r4, r5, r6, r7, r8, r9, rA_, rB_, rC_, rD_, rE_, rF_;
      // R14: exchange loads absolutely first (detection flight starts now)
      ld128o<0>(r0, rpA); ld128o<1024>(r1, rpA); ld128o<2048>(r2, rpA); ld128o<3072>(r3, rpA);
      ld128o<0>(r4, p1);  ld128o<1024>(r5, p1);  ld128o<2048>(r6, p1);  ld128o<3072>(r7, p1);
      ld128o<0>(r8, p2);  ld128o<1024>(r9, p2);  ld128o<2048>(rA_, p2); ld128o<3072>(rB_, p2);
      ld128o<0>(rC_, p3); ld128o<1024>(rD_, p3); ld128o<2048>(rE_, p3); ld128o<3072>(rF_, p3);

#pragma unroll
      for (int j = 0; j < 4; ++j)
        xh_u[j] = XH[((size_t)t * BB + brow0 + j) * HH + hcol];

      // z-finish from phase B(t-1): redB barrier-covered; overlaps load flight
      f32x4 Sz = redB[(0 * 4 + w) * 64 + lane];
      Sz += redB[(1 * 4 + w) * 64 + lane];
      Sz += redB[(2 * 4 + w) * 64 + lane];
      Sz += redB[(3 * 4 + w) * 64 + lane];
#pragma unroll
      for (int j = 0; j < 4; ++j)
        zreg[j] = sigmoid_fast(Sz[j] + bf2f(xz_u[j]));

      tie8_vm8(r0, r1, r2, r3, r4, r5, r6, r7);
      unsigned bad0 = (CHK4(r0) | CHK4(r1) | CHK4(r2) | CHK4(r3) |
                       CHK4(r4) | CHK4(r5) | CHK4(r6) | CHK4(r7)) & 0xFFFFu;
      if (!__all(bad0 == 0)) {
        tie8_vm0(r8, r9, rA_, rB_, rC_, rD_, rE_, rF_);   // drain queue
        poll8(rpA, p1, tag, dead, r0, r1, r2, r3, r4, r5, r6, r7);
      }
      u32x4 ah[4];
      ah[0] = pack_frag(r0, r1); ah[1] = pack_frag(r2, r3);
      ah[2] = pack_frag(r4, r5); ah[3] = pack_frag(r6, r7);
#pragma unroll
      for (int k = 0; k < 4; ++k) {
        s16x8 av = as16(ah[k]);
#pragma unroll
        for (int ct = 0; ct < 4; ++ct)
          acc[ct] = MFMA16(av, as16(wh[ct][k]), acc[ct]);
      }
      tie8_vm0(r8, r9, rA_, rB_, rC_, rD_, rE_, rF_);
      unsigned bad1 = (CHK4(r8) | CHK4(r9) | CHK4(rA_) | CHK4(rB_) |
                       CHK4(rC_) | CHK4(rD_) | CHK4(rE_) | CHK4(rF_)) & 0xFFFFu;
      if (!__all(bad1 == 0))
        poll8(p2, p3, tag, dead, r8, r9, rA_, rB_, rC_, rD_, rE_, rF_);
      u32x4 al[4];
      al[0] = pack_frag(r8, r9);  al[1] = pack_frag(rA_, rB_);
      al[2] = pack_frag(rC_, rD_); al[3] = pack_frag(rE_, rF_);
#pragma unroll
      for (int k = 0; k < 4; ++k) {
        s16x8 av = as16(al[k]);
#pragma unroll
        for (int ct = 0; ct < 4; ++ct)
          acc[ct] = MFMA16(av, as16(wh[ct][k + 4]), acc[ct]);
      }
    } else {
#pragma unroll
      for (int j = 0; j < 4; ++j)
        xh_u[j] = XH[((size_t)t * BB + brow0 + j) * HH + hcol];
    }
#pragma unroll
    for (int ct = 0; ct < 4; ++ct) redA[(w * 4 + ct) * 64 + lane] = acc[ct];
    __syncthreads();
    f32x4 S = redA[(0 * 4 + w) * 64 + lane];
    S += redA[(1 * 4 + w) * 64 + lane];
    S += redA[(2 * 4 + w) * 64 + lane];
    S += redA[(3 * 4 + w) * 64 + lane];

    float hn[4];
#pragma unroll
    for (int j = 0; j < 4; ++j) {
      float pre = S[j] + bf2f(xh_u[j]);
      float ht = tanh_fast(pre);
      hn[j] = zreg[j] * hreg[j] + (1.f - zreg[j]) * ht;
      hreg[j] = hn[j];
    }
    if (t == TT - 1) break;

    const unsigned tagn = (unsigned)(t + 1);
#pragma unroll
    for (int j = 0; j < 4; ++j)
      st_dw(spA + j * 4, ((unsigned)f2bf(hn[j]) << 16) | tagn);

    // ---------------- phase B: gates (r first, z deferred) ----------------
    u32x4 bh[4], bl[4];
    f32x4 ar[4] = {z4, z4, z4, z4};
    unsigned short xr_u[4];
    {
      const unsigned tag = tagn;
      const unsigned* p1 = rpB + 1024;
      const unsigned* p2 = rpB + 2048;
      const unsigned* p3 = rpB + 3072;
      u32x4 r0, r1, r2, r3, r4, r5, r6, r7, r8, r9, rA_, rB_, rC_, rD_, rE_, rF_;
      // R14: exchange loads absolutely first
      ld128o<0>(r0, rpB); ld128o<1024>(r1, rpB); ld128o<2048>(r2, rpB); ld128o<3072>(r3, rpB);
      ld128o<0>(r4, p1);  ld128o<1024>(r5, p1);  ld128o<2048>(r6, p1);  ld128o<3072>(r7, p1);
      ld128o<0>(r8, p2);  ld128o<1024>(r9, p2);  ld128o<2048>(rA_, p2); ld128o<3072>(rB_, p2);
      ld128o<0>(rC_, p3); ld128o<1024>(rD_, p3); ld128o<2048>(rE_, p3); ld128o<3072>(rF_, p3);

#pragma unroll
      for (int j = 0; j < 4; ++j) {
        xz_u[j] = XZ[((size_t)t * BB + brow0 + j) * HH + hcol];
        xr_u[j] = XR[((size_t)t * BB + brow0 + j) * HH + hcol];
      }
      // prefetch Vr ct=0 (both k-halves); flight overlaps exchange wait
      u32x4 vr00[4], vr01[4];
#pragma unroll
      for (int k = 0; k < 4; ++k) {
        vr00[k] = *(const u32x4*)(Vrp + (((size_t)(c4 + 0) * 32 + kw + k) * 64 + lane) * 8);
        vr01[k] = *(const u32x4*)(Vrp + (((size_t)(c4 + 0) * 32 + kw + k + 4) * 64 + lane) * 8);
      }

      tie8_vm8(r0, r1, r2, r3, r4, r5, r6, r7);
      unsigned bad0 = (CHK4(r0) | CHK4(r1) | CHK4(r2) | CHK4(r3) |
                       CHK4(r4) | CHK4(r5) | CHK4(r6) | CHK4(r7)) & 0xFFFFu;
      if (!__all(bad0 == 0)) {
        tie8_vm0(r8, r9, rA_, rB_, rC_, rD_, rE_, rF_);
        poll8(rpB, p1, tag, dead, r0, r1, r2, r3, r4, r5, r6, r7);
      }
      bh[0] = pack_frag(r0, r1); bh[1] = pack_frag(r2, r3);
      bh[2] = pack_frag(r4, r5); bh[3] = pack_frag(r6, r7);
      // r-GEMM k=0..3: ct0 prefetched, ct1..3 streamed
#pragma unroll
      for (int k = 0; k < 4; ++k)
        ar[0] = MFMA16(as16(bh[k]), as16(vr00[k]), ar[0]);
#pragma unroll
      for (int ct = 1; ct < 4; ++ct) {
        u32x4 vrk[4];
#pragma unroll
        for (int k = 0; k < 4; ++k)
          vrk[k] = *(const u32x4*)(Vrp + (((size_t)(c4 + ct) * 32 + kw + k) * 64 + lane) * 8);
#pragma unroll
        for (int k = 0; k < 4; ++k)
          ar[ct] = MFMA16(as16(bh[k]), as16(vrk[k]), ar[ct]);
      }
      tie8_vm0(r8, r9, rA_, rB_, rC_, rD_, rE_, rF_);
      unsigned bad1 = (CHK4(r8) | CHK4(r9) | CHK4(rA_) | CHK4(rB_) |
                       CHK4(rC_) | CHK4(rD_) | CHK4(rE_) | CHK4(rF_)) & 0xFFFFu;
      if (!__all(bad1 == 0))
        poll8(p2, p3, tag, dead, r8, r9, rA_, rB_, rC_, rD_, rE_, rF_);
      bl[0] = pack_frag(r8, r9);  bl[1] = pack_frag(rA_, rB_);
      bl[2] = pack_frag(rC_, rD_); bl[3] = pack_frag(rE_, rF_);
      // r-GEMM k=4..7
#pragma unroll
      for (int k = 0; k < 4; ++k)
        ar[0] = MFMA16(as16(bl[k]), as16(vr01[k]), ar[0]);
#pragma unroll
      for (int ct = 1; ct < 4; ++ct) {
        u32x4 vrk[4];
#pragma unroll
        for (int k = 0; k < 4; ++k)
          vrk[k] = *(const u32x4*)(Vrp + (((size_t)(c4 + ct) * 32 + kw + k + 4) * 64 + lane) * 8);
#pragma unroll
        for (int k = 0; k < 4; ++k)
          ar[ct] = MFMA16(as16(bl[k]), as16(vrk[k]), ar[ct]);
      }
    }
#pragma unroll
    for (int ct = 0; ct < 4; ++ct) redC[(w * 4 + ct) * 64 + lane] = ar[ct];
    __syncthreads();
    f32x4 Sr = redC[(0 * 4 + w) * 64 + lane];
    Sr += redC[(1 * 4 + w) * 64 + lane];
    Sr += redC[(2 * 4 + w) * 64 + lane];
    Sr += redC[(3 * 4 + w) * 64 + lane];

    float rh[4];
#pragma unroll
    for (int j = 0; j < 4; ++j) {
      float rv = sigmoid_fast(Sr[j] + bf2f(xr_u[j]));
      rh[j] = rv * hreg[j];
    }
#pragma unroll
    for (int j = 0; j < 4; ++j)
      st_dw(spB + j * 4, ((unsigned)f2bf(rh[j]) << 16) | tagn);

    // z-partials (resident vz; off critical path; reduce deferred to A(t+1))
    f32x4 az[4] = {z4, z4, z4, z4};
#pragma unroll
    for (int ct = 0; ct < 4; ++ct) {
#pragma unroll
      for (int k = 0; k < 4; ++k)
        az[ct] = MFMA16(as16(bh[k]), as16(vz[ct][k]), az[ct]);
#pragma unroll
      for (int k = 0; k < 4; ++k)
        az[ct] = MFMA16(as16(bl[k]), as16(vz[ct][k + 4]), az[ct]);
    }
#pragma unroll
    for (int ct = 0; ct < 4; ++ct) redB[(w * 4 + ct) * 64 + lane] = az[ct];
    __syncthreads();   // covers redB so phase A(t+1) can z-finish pre-poll
  }

  // epilogue: final h fp32 (plain stores; visible at kernel boundary)
#pragma unroll
  for (int j = 0; j < 4; ++j)
    hfinal[(size_t)(brow0 + j) * HH + hcol] = hreg[j];
}

// ============================================================================
// K5: out[b][o] = dot(h[b,:], Wo[o,:]) + bo[o]   (fp32)
// ============================================================================
__global__ void __launch_bounds__(256) k_out(const float* __restrict__ hf,
                                             const float* __restrict__ Wo,
                                             const float* __restrict__ bo,
                                             float* __restrict__ out) {
  __shared__ float hs[HH];
  const int b = blockIdx.x, tid = threadIdx.x;
  *(f32x4*)&hs[tid * 4] = *(const f32x4*)(hf + (size_t)b * HH + tid * 4);
  __syncthreads();
  float acc = bo[tid];
  const f32x4* wr = (const f32x4*)(Wo + (size_t)tid * HH);
#pragma unroll 8
  for (int k = 0; k < HH / 4; ++k) {
    f32x4 wv = wr[k];
    f32x4 hv = *(const f32x4*)&hs[k * 4];
    acc += wv[0] * hv[0] + wv[1] * hv[1] + wv[2] * hv[2] + wv[3] * hv[3];
  }
  out[(size_t)b * NOUT + tid] = acc;
}

// ============================================================================
extern "C" void kernel_launch(void* const* d_in, const int* in_sizes, int n_in,
                              void* d_out, int out_size, void* d_ws, size_t ws_size,
                              hipStream_t stream) {
  (void)in_sizes; (void)n_in; (void)out_size; (void)ws_size;
  const float* X  = (const float*)d_in[0];
  const float* Wx = (const float*)d_in[1];
  const float* bx = (const float*)d_in[2];
  const float* Wh = (const float*)d_in[3];
  const float* Uz = (const float*)d_in[4];
  const float* bz = (const float*)d_in[5];
  const float* Vz = (const float*)d_in[6];
  const float* Ur = (const float*)d_in[7];
  const float* br = (const float*)d_in[8];
  const float* Vr = (const float*)d_in[9];
  const float* Wo = (const float*)d_in[10];
  const float* bo = (const float*)d_in[11];

  char* ws = (char*)d_ws;
  unsigned short* XHp = (unsigned short*)(ws + OFF_XH);
  unsigned short* XZp = (unsigned short*)(ws + OFF_XZ);
  unsigned short* XRp = (unsigned short*)(ws + OFF_XR);
  unsigned short* Xb  = (unsigned short*)(ws + OFF_XB);
  unsigned short* Whp = (unsigned short*)(ws + OFF_WHP);
  unsigned short* Vzp = (unsigned short*)(ws + OFF_VZP);
  unsigned short* Vrp = (unsigned short*)(ws + OFF_VRP);
  unsigned short* Wxp = (unsigned short*)(ws + OFF_WXP);
  unsigned short* Uzp = (unsigned short*)(ws + OFF_UZP);
  unsigned short* Urp = (unsigned short*)(ws + OFF_URP);
  unsigned* hbp  = (unsigned*)(ws + OFF_HB);
  unsigned* hrbp = (unsigned*)(ws + OFF_HRB);
  float* hfp = (float*)(ws + OFF_HF);

  k_convert_x<<<8192, 256, 0, stream>>>(X, Xb);
  k_pack_w<<<dim3(512, 6), 256, 0, stream>>>(Wh, Vz, Vr, Wx, Uz, Ur,
                                             Whp, Vzp, Vrp, Wxp, Uzp, Urp);
  k_proj<<<dim3(512, 16, 3), 256, 0, stream>>>(Xb, Wxp, Uzp, Urp, bx, bz, br,
                                               XHp, XZp, XRp);
  k_scan<<<64, 256, 0, stream>>>(XHp, XZp, XRp, Whp, Vzp, Vrp,
                                 hbp, hrbp, hfp);
  k_out<<<64, 256, 0, stream>>>(hfp, Wo, bo, (float*)d_out);
}

// Round 14
// 3216.913 us; speedup vs baseline: 1.1376x; 1.1376x over previous
//
#include <hip/hip_runtime.h>

// ============================================================================
// GRU_29300266893722  (B=64, T=512, IN=256, H=1024, OUT=256)  -- MI355X gfx950
//
// R15 = R13 (k_scan 2990us) + the R14 idea done RIGHT. R14 (+15.7%, reverted)
// taught the mechanism: vmcnt counts ALL outstanding VMEM in issue order, so
// issuing xz/xr (HBM, ~900cy) and vr prefetch AFTER the exchange loads but
// BEFORE the vm8 tie made vm8 wait for 24/32 retires = all exchange + xzxr.
// R15 keeps the vm8 window CLEAN and retunes the second tie:
//  phase A: e16 -> z-finish -> vm8 (queue=e16: ties e0..e7 exactly) ->
//           issue xh -> half0 -> vm4 (queue=e8..e15+xh4: ties e8..e15, does
//           NOT wait xh) -> half1.
//  phase B: vr prefetch (L2, retires early) -> e16 -> vm8 (ties vr8+e0..e7)
//           -> issue xz/xr -> half0 -> vm8#2 (queue=e8..e15+xzxr8: ties
//           e8..e15, does NOT wait the HBM xz/xr; R13's vm0 here DID) ->
//           half1.
//  poll8 = R13's exact backoff (unconfound).
// History: R8 z-deferral -5.5%; R11 split-poll -11%; R12 resid-swap +5.6%
// (rev); R13 loads-before-z-finish -5% (k_scan 2990, BEST); R14 queue-
// polluted reorder +15.7% (rev).
// ============================================================================

#define BB 64
#define TT 512
#define KIN 256
#define HH 1024
#define NOUT 256

typedef float  f32x4 __attribute__((ext_vector_type(4)));
typedef short  s16x8 __attribute__((ext_vector_type(8)));
typedef unsigned int u32x4 __attribute__((ext_vector_type(4)));
typedef unsigned short u16x4 __attribute__((ext_vector_type(4)));

#define MFMA16(a, b, c) __builtin_amdgcn_mfma_f32_16x16x32_bf16((a), (b), (c), 0, 0, 0)

static __device__ __forceinline__ s16x8 as16(u32x4 v) { return __builtin_bit_cast(s16x8, v); }

static __device__ __forceinline__ unsigned short f2bf(float f) {
  unsigned u = __float_as_uint(f);
  u += 0x7FFFu + ((u >> 16) & 1u);   // round-to-nearest-even
  return (unsigned short)(u >> 16);
}
static __device__ __forceinline__ float bf2f(unsigned short h) {
  return __uint_as_float(((unsigned)h) << 16);
}

static __device__ __forceinline__ float tanh_fast(float x) {
  float xc = fminf(fmaxf(x, -15.f), 15.f);
  float e = __expf(2.f * xc);
  return (e - 1.f) / (e + 1.f);
}
static __device__ __forceinline__ float sigmoid_fast(float x) {
  float xc = fminf(fmaxf(x, -30.f), 30.f);
  return 1.f / (1.f + __expf(-xc));
}

// ---- device-scope (IF-coherent) access helpers -----------------------------
static __device__ __forceinline__ void st_dw(unsigned* p, unsigned v) {
  asm volatile("global_store_dword %0, %1, off sc0 sc1" :: "v"(p), "v"(v) : "memory");
}
template <int OFF>
static __device__ __forceinline__ void ld128o(u32x4& d, const unsigned* p) {
  asm volatile("global_load_dwordx4 %0, %1, off offset:%2 sc0 sc1"
               : "=v"(d) : "v"(p), "i"(OFF));
}
// ties: vmcnt retires in issue order; N = loads allowed to stay outstanding
static __device__ __forceinline__ void tie8_vm8(u32x4& a0, u32x4& a1, u32x4& a2, u32x4& a3,
                                                u32x4& a4, u32x4& a5, u32x4& a6, u32x4& a7) {
  asm volatile("s_waitcnt vmcnt(8)"
               : "+v"(a0), "+v"(a1), "+v"(a2), "+v"(a3),
                 "+v"(a4), "+v"(a5), "+v"(a6), "+v"(a7) :: "memory");
}
static __device__ __forceinline__ void tie8_vm4(u32x4& a0, u32x4& a1, u32x4& a2, u32x4& a3,
                                                u32x4& a4, u32x4& a5, u32x4& a6, u32x4& a7) {
  asm volatile("s_waitcnt vmcnt(4)"
               : "+v"(a0), "+v"(a1), "+v"(a2), "+v"(a3),
                 "+v"(a4), "+v"(a5), "+v"(a6), "+v"(a7) :: "memory");
}
static __device__ __forceinline__ void tie8_vm0(u32x4& a0, u32x4& a1, u32x4& a2, u32x4& a3,
                                                u32x4& a4, u32x4& a5, u32x4& a6, u32x4& a7) {
  asm volatile("s_waitcnt vmcnt(0)"
               : "+v"(a0), "+v"(a1), "+v"(a2), "+v"(a3),
                 "+v"(a4), "+v"(a5), "+v"(a6), "+v"(a7) :: "memory");
}

#define CHK4(R) (((R).x ^ tag) | ((R).y ^ tag) | ((R).z ^ tag) | ((R).w ^ tag))

// pack two tagged-dword quads (cols j0..3, j4..7) into one bf16x8 frag quad
static __device__ __forceinline__ unsigned pk(unsigned hi, unsigned lo) {
  return __builtin_amdgcn_perm(hi, lo, 0x07060302u);
}
static __device__ __forceinline__ u32x4 pack_frag(u32x4 a, u32x4 b) {
  u32x4 r;
  r.x = pk(a.y, a.x); r.y = pk(a.w, a.z);
  r.z = pk(b.y, b.x); r.w = pk(b.w, b.z);
  return r;
}

// slow path: poll one half (2 base pointers, 8 regs) to completion w/ backoff
// (R13's exact version)
static __device__ __forceinline__ void poll8(
    const unsigned* pa, const unsigned* pb, unsigned tag, bool& dead,
    u32x4& r0, u32x4& r1, u32x4& r2, u32x4& r3,
    u32x4& r4, u32x4& r5, u32x4& r6, u32x4& r7) {
  int guard = 0;
  while (true) {
    ld128o<0>(r0, pa); ld128o<1024>(r1, pa); ld128o<2048>(r2, pa); ld128o<3072>(r3, pa);
    ld128o<0>(r4, pb); ld128o<1024>(r5, pb); ld128o<2048>(r6, pb); ld128o<3072>(r7, pb);
    tie8_vm0(r0, r1, r2, r3, r4, r5, r6, r7);
    unsigned bad = (CHK4(r0) | CHK4(r1) | CHK4(r2) | CHK4(r3) |
                    CHK4(r4) | CHK4(r5) | CHK4(r6) | CHK4(r7)) & 0xFFFFu;
    if (__all(bad == 0)) break;
    if (dead || ++guard > 4096) { dead = true; break; }
    if (guard > 1) {
      if (guard < 6) __builtin_amdgcn_s_sleep(2);
      else           __builtin_amdgcn_s_sleep(4);
    }
  }
}

// ---- workspace layout ------------------------------------------------------
static constexpr size_t SZ_XP   = (size_t)TT * BB * HH * 2;       // 64 MB
static constexpr size_t OFF_XH  = 0;
static constexpr size_t OFF_XZ  = OFF_XH + SZ_XP;
static constexpr size_t OFF_XR  = OFF_XZ + SZ_XP;
static constexpr size_t OFF_XB  = OFF_XR + SZ_XP;                 // X bf16
static constexpr size_t OFF_WHP = OFF_XB + (size_t)BB * TT * KIN * 2;
static constexpr size_t OFF_VZP = OFF_WHP + (size_t)HH * HH * 2;
static constexpr size_t OFF_VRP = OFF_VZP + (size_t)HH * HH * 2;
static constexpr size_t OFF_WXP = OFF_VRP + (size_t)HH * HH * 2;
static constexpr size_t OFF_UZP = OFF_WXP + (size_t)HH * KIN * 2;
static constexpr size_t OFF_URP = OFF_UZP + (size_t)HH * KIN * 2;
static constexpr size_t OFF_HB  = OFF_URP + (size_t)HH * KIN * 2; // 4*16*1024 tagged dwords
static constexpr size_t OFF_HRB = OFF_HB + (size_t)4 * 16 * HH * 4;
static constexpr size_t OFF_HF  = OFF_HRB + (size_t)4 * 16 * HH * 4;  // final h fp32

// ============================================================================
// K1: X fp32 -> bf16
// ============================================================================
__global__ void __launch_bounds__(256) k_convert_x(const float* __restrict__ X,
                                                   unsigned short* __restrict__ Xb) {
  size_t i = ((size_t)blockIdx.x * 256 + threadIdx.x) * 4;
  f32x4 v = *(const f32x4*)(X + i);
  u16x4 o = { f2bf(v[0]), f2bf(v[1]), f2bf(v[2]), f2bf(v[3]) };
  *(u16x4*)(Xb + i) = o;
}

// ============================================================================
// K2: pack weights W[1024][K] fp32 -> bf16 MFMA B-fragment layout
// ============================================================================
__global__ void __launch_bounds__(256) k_pack_w(
    const float* __restrict__ Wh, const float* __restrict__ Vz, const float* __restrict__ Vr,
    const float* __restrict__ Wx, const float* __restrict__ Uz, const float* __restrict__ Ur,
    unsigned short* __restrict__ Whp, unsigned short* __restrict__ Vzp, unsigned short* __restrict__ Vrp,
    unsigned short* __restrict__ Wxp, unsigned short* __restrict__ Uzp, unsigned short* __restrict__ Urp) {
  int z = blockIdx.y;
  const float* src; unsigned short* dst; int K;
  switch (z) {
    case 0: src = Wh; dst = Whp; K = 1024; break;
    case 1: src = Vz; dst = Vzp; K = 1024; break;
    case 2: src = Vr; dst = Vrp; K = 1024; break;
    case 3: src = Wx; dst = Wxp; K = 256;  break;
    case 4: src = Uz; dst = Uzp; K = 256;  break;
    default: src = Ur; dst = Urp; K = 256; break;
  }
  int KK = K >> 5;
  int total = 64 * KK * 64;
  int tau = blockIdx.x * 256 + threadIdx.x;
  if (tau >= total) return;
  int lane = tau & 63;
  int kk = (tau >> 6) % KK;
  int ct = tau / (KK * 64);
  int q = lane >> 4, cl = lane & 15;
  const float* s = src + (size_t)(ct * 16 + cl) * K + kk * 32 + q * 8;
  f32x4 v0 = *(const f32x4*)s;
  f32x4 v1 = *(const f32x4*)(s + 4);
  u32x4 o;
  o.x = (unsigned)f2bf(v0[0]) | ((unsigned)f2bf(v0[1]) << 16);
  o.y = (unsigned)f2bf(v0[2]) | ((unsigned)f2bf(v0[3]) << 16);
  o.z = (unsigned)f2bf(v1[0]) | ((unsigned)f2bf(v1[1]) << 16);
  o.w = (unsigned)f2bf(v1[2]) | ((unsigned)f2bf(v1[3]) << 16);
  *(u32x4*)(dst + (size_t)tau * 8) = o;
}

// ============================================================================
// K3: XH/XZ/XR[t][b][h] (bf16) = X @ {Wx,Uz,Ur}^T + bias.  grid (512,16,3).
// ============================================================================
__global__ void __launch_bounds__(256) k_proj(
    const unsigned short* __restrict__ Xb,
    const unsigned short* __restrict__ Wxp, const unsigned short* __restrict__ Uzp,
    const unsigned short* __restrict__ Urp,
    const float* __restrict__ bx, const float* __restrict__ bz, const float* __restrict__ br,
    unsigned short* __restrict__ XH, unsigned short* __restrict__ XZ, unsigned short* __restrict__ XR) {
  __shared__ u32x4 As[4 * 8 * 64];  // 32 KB
  const int tid = threadIdx.x;
  const int mb = blockIdx.x, cb = blockIdx.y, mu = blockIdx.z;

#pragma unroll
  for (int i = 0; i < 8; ++i) {
    int fid = i * 256 + tid;
    int lane = fid & 63, kk = (fid >> 6) & 7, rt = fid >> 9;
    int q = lane >> 4, cl = lane & 15;
    int mrow = mb * 64 + rt * 16 + cl;
    As[fid] = *(const u32x4*)(Xb + (size_t)mrow * KIN + kk * 32 + q * 8);
  }
  __syncthreads();

  const int lane = tid & 63, w = tid >> 6;
  const int q = lane >> 4, cl = lane & 15;
  const unsigned short* Bp = (mu == 0) ? Wxp : (mu == 1) ? Uzp : Urp;
  const float* bias        = (mu == 0) ? bx  : (mu == 1) ? bz  : br;
  unsigned short* Dst      = (mu == 0) ? XH  : (mu == 1) ? XZ  : XR;

  f32x4 z4 = {0.f, 0.f, 0.f, 0.f};
  f32x4 acc[4] = {z4, z4, z4, z4};
  const int ctg = cb * 4 + w;
#pragma unroll
  for (int kk = 0; kk < 8; ++kk) {
    u32x4 b = *(const u32x4*)(Bp + ((size_t)(ctg * 8 + kk) * 64 + lane) * 8);
#pragma unroll
    for (int rt = 0; rt < 4; ++rt)
      acc[rt] = MFMA16(as16(As[(rt * 8 + kk) * 64 + lane]), as16(b), acc[rt]);
  }
  const int col = cb * 64 + w * 16 + cl;
  const float bv = bias[col];
#pragma unroll
  for (int rt = 0; rt < 4; ++rt) {
#pragma unroll
    for (int j = 0; j < 4; ++j) {
      int m = mb * 64 + rt * 16 + q * 4 + j;   // m = b*512 + t
      int t = m & (TT - 1), b = m >> 9;
      Dst[((size_t)t * BB + b) * HH + col] = f2bf(acc[rt][j] + bv);
    }
  }
}

// ============================================================================
// K4: persistent scan, tag-in-data, fragment-major exchange buffers.
//   64 blocks x 256 threads. chain g = blk>>4, col-block c = blk&15.
//   wave w: K-slice [256w,256w+256), owns cols c*64+w*16+cl, rows q*4+j.
//   R15: clean vm8 windows; slow HBM loads issued after the first tie.
// ============================================================================
__global__ void __launch_bounds__(256, 1) k_scan(
    const unsigned short* __restrict__ XH, const unsigned short* __restrict__ XZ,
    const unsigned short* __restrict__ XR,
    const unsigned short* __restrict__ Whp, const unsigned short* __restrict__ Vzp,
    const unsigned short* __restrict__ Vrp,
    unsigned* __restrict__ hb32all, unsigned* __restrict__ hrb32all,
    float* __restrict__ hfinal) {
  __shared__ f32x4 redA[16 * 64];  // 16 KB
  __shared__ f32x4 redB[16 * 64];  // 16 KB  (z-partials; reduced next step)
  __shared__ f32x4 redC[16 * 64];  // 16 KB

  const int tid = threadIdx.x;
  const int lane = tid & 63, w = tid >> 6;
  const int q = lane >> 4, cl = lane & 15;
  const int blk = blockIdx.x;
  const int g = blk >> 4, c = blk & 15;   // chain, col-block
  const int c4 = c * 4, kw = w * 8;

  unsigned* hb  = hb32all  + (size_t)g * 16 * HH;
  unsigned* hrb = hrb32all + (size_t)g * 16 * HH;

  // resident weight fragments: Wh + Vz (256 VGPRs); Vr streamed per step
  u32x4 wh[4][8], vz[4][8];
#pragma unroll
  for (int ct = 0; ct < 4; ++ct)
#pragma unroll
    for (int k = 0; k < 8; ++k) {
      size_t fi = (((size_t)(c4 + ct) * 32 + kw + k) * 64 + lane) * 8;
      wh[ct][k] = *(const u32x4*)(Whp + fi);
      vz[ct][k] = *(const u32x4*)(Vzp + fi);
    }

  const int hcol = c * 64 + w * 16 + cl;         // owned output column
  const int brow0 = g * 16 + q * 4;              // owned batch rows (+j)

  // consumer read bases (fragment-major): buf + w*4096 + lane*4 dwords
  const unsigned* rpA = hrb + w * 4096 + lane * 4;
  const unsigned* rpB = hb  + w * 4096 + lane * 4;
  // producer store bases
  const unsigned C = (unsigned)hcol;
  const unsigned sbase = ((C >> 8) * 8 + ((C >> 5) & 7)) * 512 + ((C >> 2) & 1) * 256 +
                         (((C >> 3) & 3) * 16 + q * 4) * 4 + (C & 3);
  unsigned* spA = hb  + sbase;    // row j store at + j*4
  unsigned* spB = hrb + sbase;

  const f32x4 z4 = {0.f, 0.f, 0.f, 0.f};
  f32x4 hreg = z4, zreg = z4;
  unsigned short xz_u[4] = {0, 0, 0, 0};  // carried across steps (deferred z)
  bool dead = false;

  for (int t = 0; t < TT; ++t) {
    // ---------------- phase A: h update ----------------
    unsigned short xh_u[4];
    f32x4 acc[4] = {z4, z4, z4, z4};
    if (t > 0) {
      const unsigned tag = (unsigned)t;
      const unsigned* p1 = rpA + 1024;
      const unsigned* p2 = rpA + 2048;
      const unsigned* p3 = rpA + 3072;
      u32x4 r0, r1, r2, r3, r4, r5, r6, r7, r8, r9, rA_, rB_, rC_, rD_, rE_, rF_;
      // exchange loads FIRST; queue holds ONLY these 16 at the vm8 tie
      ld128o<0>(r0, rpA); ld128o<1024>(r1, rpA); ld128o<2048>(r2, rpA); ld128o<3072>(r3, rpA);
      ld128o<0>(r4, p1);  ld128o<1024>(r5, p1);  ld128o<2048>(r6, p1);  ld128o<3072>(r7, p1);
      ld128o<0>(r8, p2);  ld128o<1024>(r9, p2);  ld128o<2048>(rA_, p2); ld128o<3072>(rB_, p2);
      ld128o<0>(rC_, p3); ld128o<1024>(rD_, p3); ld128o<2048>(rE_, p3); ld128o<3072>(rF_, p3);

      // z-finish from phase B(t-1): LDS/VALU only -- overlaps load flight
      f32x4 Sz = redB[(0 * 4 + w) * 64 + lane];
      Sz += redB[(1 * 4 + w) * 64 + lane];
      Sz += redB[(2 * 4 + w) * 64 + lane];
      Sz += redB[(3 * 4 + w) * 64 + lane];
#pragma unroll
      for (int j = 0; j < 4; ++j)
        zreg[j] = sigmoid_fast(Sz[j] + bf2f(xz_u[j]));

      tie8_vm8(r0, r1, r2, r3, r4, r5, r6, r7);   // queue=16 -> ties e0..e7
      // issue xh AFTER the tie (flight overlaps MFMA; vm4 below skips them)
#pragma unroll
      for (int j = 0; j < 4; ++j)
        xh_u[j] = XH[((size_t)t * BB + brow0 + j) * HH + hcol];
      unsigned bad0 = (CHK4(r0) | CHK4(r1) | CHK4(r2) | CHK4(r3) |
                       CHK4(r4) | CHK4(r5) | CHK4(r6) | CHK4(r7)) & 0xFFFFu;
      if (!__all(bad0 == 0)) {
        tie8_vm0(r8, r9, rA_, rB_, rC_, rD_, rE_, rF_);   // drain queue
        poll8(rpA, p1, tag, dead, r0, r1, r2, r3, r4, r5, r6, r7);
      }
      u32x4 ah[4];
      ah[0] = pack_frag(r0, r1); ah[1] = pack_frag(r2, r3);
      ah[2] = pack_frag(r4, r5); ah[3] = pack_frag(r6, r7);
#pragma unroll
      for (int k = 0; k < 4; ++k) {
        s16x8 av = as16(ah[k]);
#pragma unroll
        for (int ct = 0; ct < 4; ++ct)
          acc[ct] = MFMA16(av, as16(wh[ct][k]), acc[ct]);
      }
      // queue = e8..e15 + xh(4): vmcnt(4) ties e8..e15 WITHOUT waiting xh
      tie8_vm4(r8, r9, rA_, rB_, rC_, rD_, rE_, rF_);
      unsigned bad1 = (CHK4(r8) | CHK4(r9) | CHK4(rA_) | CHK4(rB_) |
                       CHK4(rC_) | CHK4(rD_) | CHK4(rE_) | CHK4(rF_)) & 0xFFFFu;
      if (!__all(bad1 == 0))
        poll8(p2, p3, tag, dead, r8, r9, rA_, rB_, rC_, rD_, rE_, rF_);
      u32x4 al[4];
      al[0] = pack_frag(r8, r9);  al[1] = pack_frag(rA_, rB_);
      al[2] = pack_frag(rC_, rD_); al[3] = pack_frag(rE_, rF_);
#pragma unroll
      for (int k = 0; k < 4; ++k) {
        s16x8 av = as16(al[k]);
#pragma unroll
        for (int ct = 0; ct < 4; ++ct)
          acc[ct] = MFMA16(av, as16(wh[ct][k + 4]), acc[ct]);
      }
    } else {
#pragma unroll
      for (int j = 0; j < 4; ++j)
        xh_u[j] = XH[((size_t)t * BB + brow0 + j) * HH + hcol];
    }
#pragma unroll
    for (int ct = 0; ct < 4; ++ct) redA[(w * 4 + ct) * 64 + lane] = acc[ct];
    __syncthreads();
    f32x4 S = redA[(0 * 4 + w) * 64 + lane];
    S += redA[(1 * 4 + w) * 64 + lane];
    S += redA[(2 * 4 + w) * 64 + lane];
    S += redA[(3 * 4 + w) * 64 + lane];

    float hn[4];
#pragma unroll
    for (int j = 0; j < 4; ++j) {
      float pre = S[j] + bf2f(xh_u[j]);
      float ht = tanh_fast(pre);
      hn[j] = zreg[j] * hreg[j] + (1.f - zreg[j]) * ht;
      hreg[j] = hn[j];
    }
    if (t == TT - 1) break;

    const unsigned tagn = (unsigned)(t + 1);
#pragma unroll
    for (int j = 0; j < 4; ++j)
      st_dw(spA + j * 4, ((unsigned)f2bf(hn[j]) << 16) | tagn);

    // ---------------- phase B: gates (r first, z deferred) ----------------
    u32x4 bh[4], bl[4];
    f32x4 ar[4] = {z4, z4, z4, z4};
    unsigned short xr_u[4];
    {
      const unsigned tag = tagn;
      const unsigned* p1 = rpB + 1024;
      const unsigned* p2 = rpB + 2048;
      const unsigned* p3 = rpB + 3072;
      // vr prefetch FIRST (L2-hot weights, retire before the exchange loads)
      u32x4 vr00[4], vr01[4];
#pragma unroll
      for (int k = 0; k < 4; ++k) {
        vr00[k] = *(const u32x4*)(Vrp + (((size_t)(c4 + 0) * 32 + kw + k) * 64 + lane) * 8);
        vr01[k] = *(const u32x4*)(Vrp + (((size_t)(c4 + 0) * 32 + kw + k + 4) * 64 + lane) * 8);
      }
      u32x4 r0, r1, r2, r3, r4, r5, r6, r7, r8, r9, rA_, rB_, rC_, rD_, rE_, rF_;
      ld128o<0>(r0, rpB); ld128o<1024>(r1, rpB); ld128o<2048>(r2, rpB); ld128o<3072>(r3, rpB);
      ld128o<0>(r4, p1);  ld128o<1024>(r5, p1);  ld128o<2048>(r6, p1);  ld128o<3072>(r7, p1);
      ld128o<0>(r8, p2);  ld128o<1024>(r9, p2);  ld128o<2048>(rA_, p2); ld128o<3072>(rB_, p2);
      ld128o<0>(rC_, p3); ld128o<1024>(rD_, p3); ld128o<2048>(rE_, p3); ld128o<3072>(rF_, p3);
      // queue = vr(8)+e16; vm8 -> ties vr(all, fast) + e0..e7
      tie8_vm8(r0, r1, r2, r3, r4, r5, r6, r7);
      // issue xz/xr AFTER the tie (HBM flight overlaps half0 MFMA; the
      // vm8#2 below does NOT wait them)
#pragma unroll
      for (int j = 0; j < 4; ++j) {
        xz_u[j] = XZ[((size_t)t * BB + brow0 + j) * HH + hcol];
        xr_u[j] = XR[((size_t)t * BB + brow0 + j) * HH + hcol];
      }
      unsigned bad0 = (CHK4(r0) | CHK4(r1) | CHK4(r2) | CHK4(r3) |
                       CHK4(r4) | CHK4(r5) | CHK4(r6) | CHK4(r7)) & 0xFFFFu;
      if (!__all(bad0 == 0)) {
        tie8_vm0(r8, r9, rA_, rB_, rC_, rD_, rE_, rF_);
        poll8(rpB, p1, tag, dead, r0, r1, r2, r3, r4, r5, r6, r7);
      }
      bh[0] = pack_frag(r0, r1); bh[1] = pack_frag(r2, r3);
      bh[2] = pack_frag(r4, r5); bh[3] = pack_frag(r6, r7);
      // r-GEMM k=0..3: ct0 prefetched, ct1..3 streamed
#pragma unroll
      for (int k = 0; k < 4; ++k)
        ar[0] = MFMA16(as16(bh[k]), as16(vr00[k]), ar[0]);
#pragma unroll
      for (int ct = 1; ct < 4; ++ct) {
        u32x4 vrk[4];
#pragma unroll
        for (int k = 0; k < 4; ++k)
          vrk[k] = *(const u32x4*)(Vrp + (((size_t)(c4 + ct) * 32 + kw + k) * 64 + lane) * 8);
#pragma unroll
        for (int k = 0; k < 4; ++k)
          ar[ct] = MFMA16(as16(bh[k]), as16(vrk[k]), ar[ct]);
      }
      // queue = e8..e15 + xzxr(8) [+ streamed vrk, retired under MFMA]:
      // vm8 ties e8..e15 WITHOUT waiting the HBM xz/xr (R13's vm0 did).
      tie8_vm8(r8, r9, rA_, rB_, rC_, rD_, rE_, rF_);
      unsigned bad1 = (CHK4(r8) | CHK4(r9) | CHK4(rA_) | CHK4(rB_) |
                       CHK4(rC_) | CHK4(rD_) | CHK4(rE_) | CHK4(rF_)) & 0xFFFFu;
      if (!__all(bad1 == 0))
        poll8(p2, p3, tag, dead, r8, r9, rA_, rB_, rC_, rD_, rE_, rF_);
      bl[0] = pack_frag(r8, r9);  bl[1] = pack_frag(rA_, rB_);
      bl[2] = pack_frag(rC_, rD_); bl[3] = pack_frag(rE_, rF_);
      // r-GEMM k=4..7
#pragma unroll
      for (int k = 0; k < 4; ++k)
        ar[0] = MFMA16(as16(bl[k]), as16(vr01[k]), ar[0]);
#pragma unroll
      for (int ct = 1; ct < 4; ++ct) {
        u32x4 vrk[4];
#pragma unroll
        for (int k = 0; k < 4; ++k)
          vrk[k] = *(const u32x4*)(Vrp + (((size_t)(c4 + ct) * 32 + kw + k + 4) * 64 + lane) * 8);
#pragma unroll
        for (int k = 0; k < 4; ++k)
          ar[ct] = MFMA16(as16(bl[k]), as16(vrk[k]), ar[ct]);
      }
    }
#pragma unroll
    for (int ct = 0; ct < 4; ++ct) redC[(w * 4 + ct) * 64 + lane] = ar[ct];
    __syncthreads();
    f32x4 Sr = redC[(0 * 4 + w) * 64 + lane];
    Sr += redC[(1 * 4 + w) * 64 + lane];
    Sr += redC[(2 * 4 + w) * 64 + lane];
    Sr += redC[(3 * 4 + w) * 64 + lane];

    float rh[4];
#pragma unroll
    for (int j = 0; j < 4; ++j) {
      float rv = sigmoid_fast(Sr[j] + bf2f(xr_u[j]));
      rh[j] = rv * hreg[j];
    }
#pragma unroll
    for (int j = 0; j < 4; ++j)
      st_dw(spB + j * 4, ((unsigned)f2bf(rh[j]) << 16) | tagn);

    // z-partials (resident vz; off critical path; reduce deferred to A(t+1))
    f32x4 az[4] = {z4, z4, z4, z4};
#pragma unroll
    for (int ct = 0; ct < 4; ++ct) {
#pragma unroll
      for (int k = 0; k < 4; ++k)
        az[ct] = MFMA16(as16(bh[k]), as16(vz[ct][k]), az[ct]);
#pragma unroll
      for (int k = 0; k < 4; ++k)
        az[ct] = MFMA16(as16(bl[k]), as16(vz[ct][k + 4]), az[ct]);
    }
#pragma unroll
    for (int ct = 0; ct < 4; ++ct) redB[(w * 4 + ct) * 64 + lane] = az[ct];
    __syncthreads();   // covers redB so phase A(t+1) can z-finish pre-poll
  }

  // epilogue: final h fp32 (plain stores; visible at kernel boundary)
#pragma unroll
  for (int j = 0; j < 4; ++j)
    hfinal[(size_t)(brow0 + j) * HH + hcol] = hreg[j];
}

// ============================================================================
// K5: out[b][o] = dot(h[b,:], Wo[o,:]) + bo[o]   (fp32)
// ============================================================================
__global__ void __launch_bounds__(256) k_out(const float* __restrict__ hf,
                                             const float* __restrict__ Wo,
                                             const float* __restrict__ bo,
                                             float* __restrict__ out) {
  __shared__ float hs[HH];
  const int b = blockIdx.x, tid = threadIdx.x;
  *(f32x4*)&hs[tid * 4] = *(const f32x4*)(hf + (size_t)b * HH + tid * 4);
  __syncthreads();
  float acc = bo[tid];
  const f32x4* wr = (const f32x4*)(Wo + (size_t)tid * HH);
#pragma unroll 8
  for (int k = 0; k < HH / 4; ++k) {
    f32x4 wv = wr[k];
    f32x4 hv = *(const f32x4*)&hs[k * 4];
    acc += wv[0] * hv[0] + wv[1] * hv[1] + wv[2] * hv[2] + wv[3] * hv[3];
  }
  out[(size_t)b * NOUT + tid] = acc;
}

// ============================================================================
extern "C" void kernel_launch(void* const* d_in, const int* in_sizes, int n_in,
                              void* d_out, int out_size, void* d_ws, size_t ws_size,
                              hipStream_t stream) {
  (void)in_sizes; (void)n_in; (void)out_size; (void)ws_size;
  const float* X  = (const float*)d_in[0];
  const float* Wx = (const float*)d_in[1];
  const float* bx = (const float*)d_in[2];
  const float* Wh = (const float*)d_in[3];
  const float* Uz = (const float*)d_in[4];
  const float* bz = (const float*)d_in[5];
  const float* Vz = (const float*)d_in[6];
  const float* Ur = (const float*)d_in[7];
  const float* br = (const float*)d_in[8];
  const float* Vr = (const float*)d_in[9];
  const float* Wo = (const float*)d_in[10];
  const float* bo = (const float*)d_in[11];

  char* ws = (char*)d_ws;
  unsigned short* XHp = (unsigned short*)(ws + OFF_XH);
  unsigned short* XZp = (unsigned short*)(ws + OFF_XZ);
  unsigned short* XRp = (unsigned short*)(ws + OFF_XR);
  unsigned short* Xb  = (unsigned short*)(ws + OFF_XB);
  unsigned short* Whp = (unsigned short*)(ws + OFF_WHP);
  unsigned short* Vzp = (unsigned short*)(ws + OFF_VZP);
  unsigned short* Vrp = (unsigned short*)(ws + OFF_VRP);
  unsigned short* Wxp = (unsigned short*)(ws + OFF_WXP);
  unsigned short* Uzp = (unsigned short*)(ws + OFF_UZP);
  unsigned short* Urp = (unsigned short*)(ws + OFF_URP);
  unsigned* hbp  = (unsigned*)(ws + OFF_HB);
  unsigned* hrbp = (unsigned*)(ws + OFF_HRB);
  float* hfp = (float*)(ws + OFF_HF);

  k_convert_x<<<8192, 256, 0, stream>>>(X, Xb);
  k_pack_w<<<dim3(512, 6), 256, 0, stream>>>(Wh, Vz, Vr, Wx, Uz, Ur,
                                             Whp, Vzp, Vrp, Wxp, Uzp, Urp);
  k_proj<<<dim3(512, 16, 3), 256, 0, stream>>>(Xb, Wxp, Uzp, Urp, bx, bz, br,
                                               XHp, XZp, XRp);
  k_scan<<<64, 256, 0, stream>>>(XHp, XZp, XRp, Whp, Vzp, Vrp,
                                 hbp, hrbp, hfp);
  k_out<<<64, 256, 0, stream>>>(hfp, Wo, bo, (float*)d_out);
}